// Round 1
// baseline (237.261 us; speedup 1.0000x reference)
//
#include <hip/hip_runtime.h>
#include <hip/hip_bf16.h>

typedef __attribute__((ext_vector_type(8))) short bf16x8;
typedef __attribute__((ext_vector_type(4))) float f32x4;

#define NB 4096
#define ND 512
#define MARGIN_F 0.2f

// order-preserving float -> uint encoding for atomicMax.
__device__ __forceinline__ unsigned int enc_f32(float f) {
    unsigned int b = __float_as_uint(f);
    return (b & 0x80000000u) ? ~b : (b | 0x80000000u);
}

__device__ __forceinline__ float dec_f32(unsigned int e) {
    unsigned int b = (e & 0x80000000u) ? (e & 0x7fffffffu) : ~e;
    return __uint_as_float(b);
}

__device__ __forceinline__ void gld_lds16(const void* g, void* l) {
    __builtin_amdgcn_global_load_lds((__attribute__((address_space(1))) void*)g,
                                     (__attribute__((address_space(3))) void*)l,
                                     16, 0, 0);
}

#define SBAR() asm volatile("s_barrier" ::: "memory")

// ---------------------------------------------------------------------------
// Prep: fp32 -> bf16 fragment-swizzled convert (both matrices), grid 2048.
// Blocks [0,16) additionally zero the 4096-entry rowmax array.
// Layout: chunk (rb16 = row/16, cb = col/32) is 1KB at (rb16*16+cb)*1024;
// within chunk lane L = (row%16) | (((col%32)/8)<<4) holds 8 bf16 at L*16.
// ---------------------------------------------------------------------------
__global__ __launch_bounds__(256) void k_prep(const float* __restrict__ zs,
                                              const float* __restrict__ zi,
                                              __hip_bfloat16* __restrict__ outb,
                                              unsigned int* __restrict__ rowmax) {
    const int bid = blockIdx.x;
    if (bid < 16) rowmax[bid * 256 + threadIdx.x] = 0u;

    int gid = bid * 256 + threadIdx.x;   // [0, 2*4096*64)
    int mat = gid >> 18;                 // 0 = zs, 1 = zi
    int t   = gid & 0x3FFFF;
    int si  = t >> 6;
    int L   = t & 63;
    const float* src = mat ? zi : zs;
    int row = ((si >> 4) << 4) | (L & 15);
    int col = ((si & 15) << 5) | (((L >> 4) & 3) << 3);
    const float4* p = (const float4*)(src + (size_t)row * ND + col);
    float4 f0 = p[0];
    float4 f1 = p[1];
    union { __hip_bfloat16 h[8]; bf16x8 v; } u;
    u.h[0] = __float2bfloat16(f0.x);
    u.h[1] = __float2bfloat16(f0.y);
    u.h[2] = __float2bfloat16(f0.z);
    u.h[3] = __float2bfloat16(f0.w);
    u.h[4] = __float2bfloat16(f1.x);
    u.h[5] = __float2bfloat16(f1.y);
    u.h[6] = __float2bfloat16(f1.z);
    u.h[7] = __float2bfloat16(f1.w);
    bf16x8* dst = (bf16x8*)(outb + ((size_t)mat << 21) + ((size_t)si << 9) + (L << 3));
    *dst = u.v;
}

// ---------------------------------------------------------------------------
// 256x256 tile GEMM (S = Zs . Zi^T), BK=64, 8 waves (2M x 4N), wave tile
// 128x64 = 8x4 of 16x16x32 bf16 MFMA. 4 phases per K-tile, counted vmcnt,
// raw s_barrier, setprio around MFMA clusters. LDS 128 KiB = 2 K-tile
// buffers x 4 half-tile slots of 16 KiB {A-h0, A-h1, B-h0, B-h1}.
//
// Staging ledger (2 global_load_lds per thread per half-tile):
//   prologue: T0.h0..h3, T1.h0, T1.h1 ; __syncthreads (drain, once)
//   iter kt:  P0 stages T(kt+1).h2 | P1 stages T(kt+1).h3
//             P2 stages T(kt+2).h0 | P3 stages T(kt+2).h1
//   boundary wait needs T(kt+1) landed; younger loads = T(kt+2).h0/h1
//   = 4 insts -> s_waitcnt vmcnt(4)  (vmcnt(0) only at kt==6 tail).
// Slot-overwrite safety: all ds_reads of buf[kt&1] issue in P0/P1 and are
// retired by the explicit lgkmcnt(0) before the end-P1 barrier, so P2/P3
// may overwrite h0/h1; h2/h3 are only overwritten after the boundary
// barrier of the NEXT iteration's P0/P1.  (b1 frags read in P2 touch only
// h2/h3 and are consumed in P3, before the boundary.)
// ---------------------------------------------------------------------------
__global__ __launch_bounds__(512, 2) void k_gemm_rowmax(const __hip_bfloat16* __restrict__ zsb,
                                                        const __hip_bfloat16* __restrict__ zib,
                                                        const int* __restrict__ labels,
                                                        unsigned int* __restrict__ rowmax,
                                                        float* __restrict__ p_diag) {
    __shared__ __align__(16) unsigned char lds[131072];
    __shared__ int labA[256];
    __shared__ int labB[256];

    const int tid = threadIdx.x;
    // XCD-aware swizzle: each XCD (bid&7) owns a 4(bx) x 8(by) tile region
    // -> working set 4 B-panels + 8 A-panels = 3 MB < 4 MB per-XCD L2.
    const int bid = blockIdx.x;
    const int xcd = bid & 7, lid = bid >> 3;
    const int bx = ((xcd & 3) << 2) | (lid & 3);
    const int by = ((xcd >> 2) << 3) | (lid >> 2);

    if (tid < 256) labA[tid] = labels[by * 256 + tid];
    else           labB[tid & 255] = labels[bx * 256 + (tid & 255)];

    const char* gA = (const char*)zsb;
    const char* gB = (const char*)zib;
    const int inner = (tid & 127) << 4;        // byte offset within 2KB (rb, kt) strip
    const int aB16 = by * 16 + (tid >> 7);     // staging row-block base (A)
    const int bB16 = bx * 16 + (tid >> 7);     // staging row-block base (B)

    // STAGE(kt, h): h = {0:A-h0, 1:A-h1, 2:B-h0, 3:B-h1}; 2 x 16B per thread.
#define STAGE(kt, h) do {                                                          \
        const char* _g = ((h) & 2) ? gB : gA;                                      \
        int _rb = (((h) & 2) ? bB16 : aB16) + (((h) & 1) << 3);                    \
        unsigned _ld = (((kt) & 1) << 16) + ((h) << 14) + (tid << 4);              \
        gld_lds16(_g + (((size_t)_rb) << 14) + ((kt) << 11) + inner, lds + _ld);   \
        gld_lds16(_g + (((size_t)(_rb + 4)) << 14) + ((kt) << 11) + inner,         \
                  lds + _ld + 8192);                                               \
    } while (0)

    const int w = tid >> 6, lane = tid & 63;
    const int w_m = w >> 2, w_n = w & 3;
    const unsigned fragOff = (unsigned)(lane << 4);
    const unsigned aBase = (unsigned)(w_m << 14) + fragOff;
    const unsigned bBase = 32768u + (unsigned)((w_n >> 1) << 14)
                         + (unsigned)(((w_n & 1) << 2) << 11) + fragOff;

    f32x4 acc[8][4];
#pragma unroll
    for (int i = 0; i < 8; ++i)
#pragma unroll
        for (int j = 0; j < 4; ++j)
            acc[i][j] = (f32x4){0.f, 0.f, 0.f, 0.f};

    // prologue: 6 half-tiles, then one full drain (also publishes labA/labB)
    STAGE(0, 0); STAGE(0, 1); STAGE(0, 2); STAGE(0, 3);
    STAGE(1, 0); STAGE(1, 1);
    __syncthreads();

#pragma unroll
    for (int kt = 0; kt < 8; ++kt) {
        const unsigned par = (unsigned)((kt & 1) << 16);
        bf16x8 a0[8], a1[8], b0[4], b1[4];

        // ---- P0: read k0 A+B frags; stage T(kt+1).h2; MFMA k0 x ns{0,1} ----
#pragma unroll
        for (int ms = 0; ms < 8; ++ms)
            a0[ms] = *(const bf16x8*)(lds + par + aBase + (ms << 11));
#pragma unroll
        for (int ns = 0; ns < 4; ++ns)
            b0[ns] = *(const bf16x8*)(lds + par + bBase + (ns << 11));
        if (kt < 7) STAGE(kt + 1, 2);
        __builtin_amdgcn_s_setprio(1);
#pragma unroll
        for (int ms = 0; ms < 8; ++ms)
            acc[ms][0] = __builtin_amdgcn_mfma_f32_16x16x32_bf16(a0[ms], b0[0], acc[ms][0], 0, 0, 0);
#pragma unroll
        for (int ms = 0; ms < 8; ++ms)
            acc[ms][1] = __builtin_amdgcn_mfma_f32_16x16x32_bf16(a0[ms], b0[1], acc[ms][1], 0, 0, 0);
        __builtin_amdgcn_s_setprio(0);
        SBAR();

        // ---- P1: read k1 A frags; stage T(kt+1).h3; MFMA k0 x ns{2,3} ----
#pragma unroll
        for (int ms = 0; ms < 8; ++ms)
            a1[ms] = *(const bf16x8*)(lds + par + aBase + (ms << 11) + 1024);
        if (kt < 7) STAGE(kt + 1, 3);
        __builtin_amdgcn_s_setprio(1);
#pragma unroll
        for (int ms = 0; ms < 8; ++ms)
            acc[ms][2] = __builtin_amdgcn_mfma_f32_16x16x32_bf16(a0[ms], b0[2], acc[ms][2], 0, 0, 0);
#pragma unroll
        for (int ms = 0; ms < 8; ++ms)
            acc[ms][3] = __builtin_amdgcn_mfma_f32_16x16x32_bf16(a0[ms], b0[3], acc[ms][3], 0, 0, 0);
        __builtin_amdgcn_s_setprio(0);
        // retire ALL ds_reads of buf[kt&1] (incl. a1) before freeing h0/h1
        asm volatile("s_waitcnt lgkmcnt(0)" ::: "memory");
        SBAR();

        // ---- P2: read k1 B frags (h2/h3 only); stage T(kt+2).h0; MFMA k1 x ns{0,1} ----
#pragma unroll
        for (int ns = 0; ns < 4; ++ns)
            b1[ns] = *(const bf16x8*)(lds + par + bBase + (ns << 11) + 1024);
        if (kt < 6) STAGE(kt + 2, 0);
        __builtin_amdgcn_s_setprio(1);
#pragma unroll
        for (int ms = 0; ms < 8; ++ms)
            acc[ms][0] = __builtin_amdgcn_mfma_f32_16x16x32_bf16(a1[ms], b1[0], acc[ms][0], 0, 0, 0);
#pragma unroll
        for (int ms = 0; ms < 8; ++ms)
            acc[ms][1] = __builtin_amdgcn_mfma_f32_16x16x32_bf16(a1[ms], b1[1], acc[ms][1], 0, 0, 0);
        __builtin_amdgcn_s_setprio(0);
        SBAR();

        // ---- P3: stage T(kt+2).h1; MFMA k1 x ns{2,3}; boundary wait ----
        if (kt < 6) STAGE(kt + 2, 1);
        __builtin_amdgcn_s_setprio(1);
#pragma unroll
        for (int ms = 0; ms < 8; ++ms)
            acc[ms][2] = __builtin_amdgcn_mfma_f32_16x16x32_bf16(a1[ms], b1[2], acc[ms][2], 0, 0, 0);
#pragma unroll
        for (int ms = 0; ms < 8; ++ms)
            acc[ms][3] = __builtin_amdgcn_mfma_f32_16x16x32_bf16(a1[ms], b1[3], acc[ms][3], 0, 0, 0);
        __builtin_amdgcn_s_setprio(0);
        if (kt < 6) {
            asm volatile("s_waitcnt vmcnt(4)" ::: "memory");   // T(kt+1) landed; T(kt+2).h0/h1 in flight
            SBAR();
        } else if (kt == 6) {
            asm volatile("s_waitcnt vmcnt(0)" ::: "memory");   // tail: T7 fully landed
            SBAR();
        }
    }
#undef STAGE

    // epilogue: C/D layout col = lane&15, row = (lane>>4)*4 + reg
    const int quad = lane >> 4;
    const int lcol = lane & 15;

    int lb[4];
#pragma unroll
    for (int ns = 0; ns < 4; ++ns)
        lb[ns] = labB[w_n * 64 + ns * 16 + lcol];

#pragma unroll
    for (int ms = 0; ms < 8; ++ms) {
        int la[4];
#pragma unroll
        for (int r = 0; r < 4; ++r)
            la[r] = labA[w_m * 128 + ms * 16 + quad * 4 + r];
        float mx[4] = {-3.0e38f, -3.0e38f, -3.0e38f, -3.0e38f};
#pragma unroll
        for (int ns = 0; ns < 4; ++ns) {
#pragma unroll
            for (int r = 0; r < 4; ++r) {
                float v = acc[ms][ns][r];
                if (la[r] != lb[ns] && v > mx[r]) mx[r] = v;
            }
        }
#pragma unroll
        for (int r = 0; r < 4; ++r) {
            float m = mx[r];
            m = fmaxf(m, __shfl_xor(m, 1));
            m = fmaxf(m, __shfl_xor(m, 2));
            m = fmaxf(m, __shfl_xor(m, 4));
            m = fmaxf(m, __shfl_xor(m, 8));
            if (lcol == 0 && m > -2.9e38f) {
                int rowg = by * 256 + w_m * 128 + ms * 16 + quad * 4 + r;
                atomicMax(&rowmax[rowg], enc_f32(m));
            }
        }
    }

    // diagonal blocks: p[a] = 1 - S[a][a]. Wave covers the diagonal iff its
    // 64-col window lies in its 128-row window: (w_n>>1)==w_m. Then the
    // diag frag pairs are ms = (w_n&1)*4 + ns, with frag-row == lcol.
    if (bx == by && (w_n >> 1) == w_m) {
        int r = lcol - quad * 4;
        if (r >= 0 && r < 4) {
#pragma unroll
            for (int ns = 0; ns < 4; ++ns) {
                int ms = ((w_n & 1) << 2) + ns;
                int rowg = by * 256 + w_m * 128 + ms * 16 + lcol;
                p_diag[rowg] = 1.0f - acc[ms][ns][r];
            }
        }
    }
}

// ---------------------------------------------------------------------------
// Finalize: has_neg = (rowmax != 0); n = 1 - dec(rowmax);
// per = relu(p - n + margin); masked mean -> out[0]
// ---------------------------------------------------------------------------
__global__ __launch_bounds__(1024) void k_finalize(const unsigned int* __restrict__ rowmax,
                                                   const float* __restrict__ p_diag,
                                                   float* __restrict__ out) {
    int tid = threadIdx.x;
    float sum = 0.0f;
    int cnt = 0;
#pragma unroll
    for (int it = 0; it < 4; ++it) {
        int a = tid + it * 1024;
        unsigned int e = rowmax[a];
        if (e != 0u) {
            float n = 1.0f - dec_f32(e);
            float per = p_diag[a] - n + MARGIN_F;
            if (per > 0.0f) sum += per;
            cnt++;
        }
    }
#pragma unroll
    for (int off = 32; off > 0; off >>= 1) {
        sum += __shfl_xor(sum, off);
        cnt += __shfl_xor(cnt, off);
    }
    __shared__ float sSum[16];
    __shared__ int sCnt[16];
    int w = tid >> 6, lane = tid & 63;
    if (lane == 0) { sSum[w] = sum; sCnt[w] = cnt; }
    __syncthreads();
    if (tid == 0) {
        float ts = 0.0f;
        int tc = 0;
#pragma unroll
        for (int i = 0; i < 16; ++i) { ts += sSum[i]; tc += sCnt[i]; }
        out[0] = (tc > 0) ? ts / (float)tc : 0.0f;
    }
}

extern "C" void kernel_launch(void* const* d_in, const int* in_sizes, int n_in,
                              void* d_out, int out_size, void* d_ws, size_t ws_size,
                              hipStream_t stream) {
    (void)in_sizes; (void)n_in; (void)out_size; (void)ws_size;
    const float* zs = (const float*)d_in[0];
    const float* zi = (const float*)d_in[1];
    const int* labels = (const int*)d_in[2];
    float* out = (float*)d_out;

    char* ws = (char*)d_ws;
    __hip_bfloat16* zb = (__hip_bfloat16*)ws;                       // 8 MB (zs then zi, swizzled)
    unsigned int* rowmax = (unsigned int*)(ws + (8u << 20));        // 16 KB
    float* p_diag = (float*)(ws + (8u << 20) + 16384);              // 16 KB

    k_prep<<<2048, 256, 0, stream>>>(zs, zi, zb, rowmax);
    k_gemm_rowmax<<<256, 512, 0, stream>>>(zb, zb + (size_t)NB * ND, labels, rowmax, p_diag);
    k_finalize<<<1, 1024, 0, stream>>>(rowmax, p_diag, out);
}

// Round 2
// 220.327 us; speedup vs baseline: 1.0769x; 1.0769x over previous
//
#include <hip/hip_runtime.h>
#include <hip/hip_bf16.h>

typedef __attribute__((ext_vector_type(8))) short bf16x8;
typedef __attribute__((ext_vector_type(4))) float f32x4;

#define NB 4096
#define ND 512
#define MARGIN_F 0.2f

// order-preserving float -> uint encoding for atomicMax.
__device__ __forceinline__ unsigned int enc_f32(float f) {
    unsigned int b = __float_as_uint(f);
    return (b & 0x80000000u) ? ~b : (b | 0x80000000u);
}

__device__ __forceinline__ float dec_f32(unsigned int e) {
    unsigned int b = (e & 0x80000000u) ? (e & 0x7fffffffu) : ~e;
    return __uint_as_float(b);
}

__device__ __forceinline__ void gld_lds16(const void* g, void* l) {
    __builtin_amdgcn_global_load_lds((__attribute__((address_space(1))) void*)g,
                                     (__attribute__((address_space(3))) void*)l,
                                     16, 0, 0);
}

#define SBAR() asm volatile("s_barrier" ::: "memory")

// ---------------------------------------------------------------------------
// Prep: fp32 -> bf16 fragment-swizzled convert (both matrices), grid 2048.
// Blocks [0,16) additionally zero the 4096-entry rowmax array.
// Layout: chunk (rb16 = row/16, cb = col/32) is 1KB at (rb16*16+cb)*1024;
// within chunk lane L = (row%16) | (((col%32)/8)<<4) holds 8 bf16 at L*16.
// ---------------------------------------------------------------------------
__global__ __launch_bounds__(256) void k_prep(const float* __restrict__ zs,
                                              const float* __restrict__ zi,
                                              __hip_bfloat16* __restrict__ outb,
                                              unsigned int* __restrict__ rowmax) {
    const int bid = blockIdx.x;
    if (bid < 16) rowmax[bid * 256 + threadIdx.x] = 0u;

    int gid = bid * 256 + threadIdx.x;   // [0, 2*4096*64)
    int mat = gid >> 18;                 // 0 = zs, 1 = zi
    int t   = gid & 0x3FFFF;
    int si  = t >> 6;
    int L   = t & 63;
    const float* src = mat ? zi : zs;
    int row = ((si >> 4) << 4) | (L & 15);
    int col = ((si & 15) << 5) | (((L >> 4) & 3) << 3);
    const float4* p = (const float4*)(src + (size_t)row * ND + col);
    float4 f0 = p[0];
    float4 f1 = p[1];
    union { __hip_bfloat16 h[8]; bf16x8 v; } u;
    u.h[0] = __float2bfloat16(f0.x);
    u.h[1] = __float2bfloat16(f0.y);
    u.h[2] = __float2bfloat16(f0.z);
    u.h[3] = __float2bfloat16(f0.w);
    u.h[4] = __float2bfloat16(f1.x);
    u.h[5] = __float2bfloat16(f1.y);
    u.h[6] = __float2bfloat16(f1.z);
    u.h[7] = __float2bfloat16(f1.w);
    bf16x8* dst = (bf16x8*)(outb + ((size_t)mat << 21) + ((size_t)si << 9) + (L << 3));
    *dst = u.v;
}

// ---------------------------------------------------------------------------
// 256x256 tile GEMM (S = Zs . Zi^T), BK=64, 8 waves (2M x 4N), wave tile
// 128x64. Quadrant schedule (low register pressure): per K-tile, 4 phases,
// each reads 4 A-frags (die at phase end) + at most 4 live B-frags:
//   P0: {b0 (k0), a(mh0,k0)} -> acc[0..3] ; P1: {a(mh1,k0)} -> acc[4..7]
//   P2: {b1 (k1), a(mh0,k1)} -> acc[0..3] ; P3: {a(mh1,k1)} -> acc[4..7]
// Live frag VGPRs <= 32 (vs 96 in the previous schedule, which spilled
// ~1 GB of scratch at the 128-VGPR budget: round-1 WRITE_SIZE evidence).
//
// Staging ledger (2 global_load_lds per thread per half-tile; h = {0:A-h0,
// 1:A-h1, 2:B-h0, 3:B-h1}):
//   A halves are read in EVERY phase -> may only be staged into the
//   opposite-parity buffer: T(kt+1).h0 in P0, T(kt+1).h1 in P1.
//   B reads of the current buffer finish in P2 (b1 consumed by P2's MFMA
//   before the P2->P3 barrier) -> same-parity T(kt+2).h2/h3 staged in P3.
//   prologue: T0.h0..h3 + T1.h2,h3 ; __syncthreads (full drain, once).
//   boundary (end P3): queue = [T(kt+1).h2h3(4), T(kt+1).h0(2), h1(2),
//   T(kt+2).h2h3(4)] -> s_waitcnt vmcnt(4) retires exactly all of T(kt+1),
//   keeps T(kt+2).h2h3 in flight. vmcnt(0) only at kt==6 (tail).
// ---------------------------------------------------------------------------
__global__ __launch_bounds__(512, 2) void k_gemm_rowmax(const __hip_bfloat16* __restrict__ zsb,
                                                        const __hip_bfloat16* __restrict__ zib,
                                                        const int* __restrict__ labels,
                                                        unsigned int* __restrict__ rowmax,
                                                        float* __restrict__ p_diag) {
    __shared__ __align__(16) unsigned char lds[131072];
    __shared__ int labA[256];
    __shared__ int labB[256];

    const int tid = threadIdx.x;
    // XCD-aware swizzle: each XCD (bid&7) owns a 4(bx) x 8(by) tile region
    // -> working set 4 B-panels + 8 A-panels = 3 MB < 4 MB per-XCD L2.
    const int bid = blockIdx.x;
    const int xcd = bid & 7, lid = bid >> 3;
    const int bx = ((xcd & 3) << 2) | (lid & 3);
    const int by = ((xcd >> 2) << 3) | (lid >> 2);

    if (tid < 256) labA[tid] = labels[by * 256 + tid];
    else           labB[tid & 255] = labels[bx * 256 + (tid & 255)];

    const char* gA = (const char*)zsb;
    const char* gB = (const char*)zib;
    const int inner = (tid & 127) << 4;        // byte offset within 2KB (rb, kt) strip
    const int aB16 = by * 16 + (tid >> 7);     // staging row-block base (A)
    const int bB16 = bx * 16 + (tid >> 7);     // staging row-block base (B)

    // STAGE(kt, h): 2 x 16B per thread into half-tile slot h of buf[kt&1].
#define STAGE(kt, h) do {                                                          \
        const char* _g = ((h) & 2) ? gB : gA;                                      \
        int _rb = (((h) & 2) ? bB16 : aB16) + (((h) & 1) << 3);                    \
        unsigned _ld = (((kt) & 1) << 16) + ((h) << 14) + (tid << 4);              \
        gld_lds16(_g + (((size_t)_rb) << 14) + ((kt) << 11) + inner, lds + _ld);   \
        gld_lds16(_g + (((size_t)(_rb + 4)) << 14) + ((kt) << 11) + inner,         \
                  lds + _ld + 8192);                                               \
    } while (0)

    const int w = tid >> 6, lane = tid & 63;
    const int w_m = w >> 2, w_n = w & 3;
    const unsigned fragOff = (unsigned)(lane << 4);
    const unsigned aBase = (unsigned)(w_m << 14) + fragOff;
    const unsigned bBase = 32768u + (unsigned)((w_n >> 1) << 14)
                         + (unsigned)(((w_n & 1) << 2) << 11) + fragOff;

    f32x4 acc[8][4];
#pragma unroll
    for (int i = 0; i < 8; ++i)
#pragma unroll
        for (int j = 0; j < 4; ++j)
            acc[i][j] = (f32x4){0.f, 0.f, 0.f, 0.f};

    // prologue: T0 fully + T1's B halves, then one full drain
    STAGE(0, 0); STAGE(0, 1); STAGE(0, 2); STAGE(0, 3);
    STAGE(1, 2); STAGE(1, 3);
    __syncthreads();

#pragma unroll
    for (int kt = 0; kt < 8; ++kt) {
        const unsigned par = (unsigned)((kt & 1) << 16);
        bf16x8 a[4], b[4];

        // ---- P0: read b0(k0) + a(mh0,k0); stage T(kt+1).h0; MFMA acc[0..3] ----
#pragma unroll
        for (int ns = 0; ns < 4; ++ns)
            b[ns] = *(const bf16x8*)(lds + par + bBase + (ns << 11));
#pragma unroll
        for (int ms = 0; ms < 4; ++ms)
            a[ms] = *(const bf16x8*)(lds + par + aBase + (ms << 11));
        if (kt < 7) STAGE(kt + 1, 0);
        __builtin_amdgcn_s_setprio(1);
#pragma unroll
        for (int ms = 0; ms < 4; ++ms)
#pragma unroll
            for (int ns = 0; ns < 4; ++ns)
                acc[ms][ns] = __builtin_amdgcn_mfma_f32_16x16x32_bf16(a[ms], b[ns], acc[ms][ns], 0, 0, 0);
        __builtin_amdgcn_s_setprio(0);
        SBAR();

        // ---- P1: read a(mh1,k0); stage T(kt+1).h1; MFMA acc[4..7] ----
#pragma unroll
        for (int ms = 0; ms < 4; ++ms)
            a[ms] = *(const bf16x8*)(lds + par + aBase + ((4 + ms) << 11));
        if (kt < 7) STAGE(kt + 1, 1);
        __builtin_amdgcn_s_setprio(1);
#pragma unroll
        for (int ms = 0; ms < 4; ++ms)
#pragma unroll
            for (int ns = 0; ns < 4; ++ns)
                acc[4 + ms][ns] = __builtin_amdgcn_mfma_f32_16x16x32_bf16(a[ms], b[ns], acc[4 + ms][ns], 0, 0, 0);
        __builtin_amdgcn_s_setprio(0);
        SBAR();

        // ---- P2: read b1(k1) + a(mh0,k1); MFMA acc[0..3] ----
#pragma unroll
        for (int ns = 0; ns < 4; ++ns)
            b[ns] = *(const bf16x8*)(lds + par + bBase + (ns << 11) + 1024);
#pragma unroll
        for (int ms = 0; ms < 4; ++ms)
            a[ms] = *(const bf16x8*)(lds + par + aBase + (ms << 11) + 1024);
        __builtin_amdgcn_s_setprio(1);
#pragma unroll
        for (int ms = 0; ms < 4; ++ms)
#pragma unroll
            for (int ns = 0; ns < 4; ++ns)
                acc[ms][ns] = __builtin_amdgcn_mfma_f32_16x16x32_bf16(a[ms], b[ns], acc[ms][ns], 0, 0, 0);
        __builtin_amdgcn_s_setprio(0);
        SBAR();

        // ---- P3: read a(mh1,k1); stage T(kt+2).h2,h3; MFMA acc[4..7]; boundary ----
#pragma unroll
        for (int ms = 0; ms < 4; ++ms)
            a[ms] = *(const bf16x8*)(lds + par + aBase + ((4 + ms) << 11) + 1024);
        if (kt < 6) { STAGE(kt + 2, 2); STAGE(kt + 2, 3); }
        __builtin_amdgcn_s_setprio(1);
#pragma unroll
        for (int ms = 0; ms < 4; ++ms)
#pragma unroll
            for (int ns = 0; ns < 4; ++ns)
                acc[4 + ms][ns] = __builtin_amdgcn_mfma_f32_16x16x32_bf16(a[ms], b[ns], acc[4 + ms][ns], 0, 0, 0);
        __builtin_amdgcn_s_setprio(0);
        if (kt < 6) {
            asm volatile("s_waitcnt vmcnt(4)" ::: "memory");   // all of T(kt+1) landed
            SBAR();
        } else if (kt == 6) {
            asm volatile("s_waitcnt vmcnt(0)" ::: "memory");   // tail: T7 fully landed
            SBAR();
        }
    }
#undef STAGE

    // epilogue: C/D layout col = lane&15, row = (lane>>4)*4 + reg
    const int quad = lane >> 4;
    const int lcol = lane & 15;

    int lb[4];
#pragma unroll
    for (int ns = 0; ns < 4; ++ns)
        lb[ns] = labB[w_n * 64 + ns * 16 + lcol];

#pragma unroll
    for (int ms = 0; ms < 8; ++ms) {
        int la[4];
#pragma unroll
        for (int r = 0; r < 4; ++r)
            la[r] = labA[w_m * 128 + ms * 16 + quad * 4 + r];
        float mx[4] = {-3.0e38f, -3.0e38f, -3.0e38f, -3.0e38f};
#pragma unroll
        for (int ns = 0; ns < 4; ++ns) {
#pragma unroll
            for (int r = 0; r < 4; ++r) {
                float v = acc[ms][ns][r];
                if (la[r] != lb[ns] && v > mx[r]) mx[r] = v;
            }
        }
#pragma unroll
        for (int r = 0; r < 4; ++r) {
            float m = mx[r];
            m = fmaxf(m, __shfl_xor(m, 1));
            m = fmaxf(m, __shfl_xor(m, 2));
            m = fmaxf(m, __shfl_xor(m, 4));
            m = fmaxf(m, __shfl_xor(m, 8));
            if (lcol == 0 && m > -2.9e38f) {
                int rowg = by * 256 + w_m * 128 + ms * 16 + quad * 4 + r;
                atomicMax(&rowmax[rowg], enc_f32(m));
            }
        }
    }

    // diagonal blocks: p[a] = 1 - S[a][a]. Wave covers the diagonal iff its
    // 64-col window lies in its 128-row window: (w_n>>1)==w_m. Then the
    // diag frag pairs are ms = (w_n&1)*4 + ns, with frag-row == lcol.
    if (bx == by && (w_n >> 1) == w_m) {
        int r = lcol - quad * 4;
        if (r >= 0 && r < 4) {
#pragma unroll
            for (int ns = 0; ns < 4; ++ns) {
                int ms = ((w_n & 1) << 2) + ns;
                int rowg = by * 256 + w_m * 128 + ms * 16 + lcol;
                p_diag[rowg] = 1.0f - acc[ms][ns][r];
            }
        }
    }
}

// ---------------------------------------------------------------------------
// Finalize: has_neg = (rowmax != 0); n = 1 - dec(rowmax);
// per = relu(p - n + margin); masked mean -> out[0]
// ---------------------------------------------------------------------------
__global__ __launch_bounds__(1024) void k_finalize(const unsigned int* __restrict__ rowmax,
                                                   const float* __restrict__ p_diag,
                                                   float* __restrict__ out) {
    int tid = threadIdx.x;
    float sum = 0.0f;
    int cnt = 0;
#pragma unroll
    for (int it = 0; it < 4; ++it) {
        int a = tid + it * 1024;
        unsigned int e = rowmax[a];
        if (e != 0u) {
            float n = 1.0f - dec_f32(e);
            float per = p_diag[a] - n + MARGIN_F;
            if (per > 0.0f) sum += per;
            cnt++;
        }
    }
#pragma unroll
    for (int off = 32; off > 0; off >>= 1) {
        sum += __shfl_xor(sum, off);
        cnt += __shfl_xor(cnt, off);
    }
    __shared__ float sSum[16];
    __shared__ int sCnt[16];
    int w = tid >> 6, lane = tid & 63;
    if (lane == 0) { sSum[w] = sum; sCnt[w] = cnt; }
    __syncthreads();
    if (tid == 0) {
        float ts = 0.0f;
        int tc = 0;
#pragma unroll
        for (int i = 0; i < 16; ++i) { ts += sSum[i]; tc += sCnt[i]; }
        out[0] = (tc > 0) ? ts / (float)tc : 0.0f;
    }
}

extern "C" void kernel_launch(void* const* d_in, const int* in_sizes, int n_in,
                              void* d_out, int out_size, void* d_ws, size_t ws_size,
                              hipStream_t stream) {
    (void)in_sizes; (void)n_in; (void)out_size; (void)ws_size;
    const float* zs = (const float*)d_in[0];
    const float* zi = (const float*)d_in[1];
    const int* labels = (const int*)d_in[2];
    float* out = (float*)d_out;

    char* ws = (char*)d_ws;
    __hip_bfloat16* zb = (__hip_bfloat16*)ws;                       // 8 MB (zs then zi, swizzled)
    unsigned int* rowmax = (unsigned int*)(ws + (8u << 20));        // 16 KB
    float* p_diag = (float*)(ws + (8u << 20) + 16384);              // 16 KB

    k_prep<<<2048, 256, 0, stream>>>(zs, zi, zb, rowmax);
    k_gemm_rowmax<<<256, 512, 0, stream>>>(zb, zb + (size_t)NB * ND, labels, rowmax, p_diag);
    k_finalize<<<1, 1024, 0, stream>>>(rowmax, p_diag, out);
}

// Round 3
// 99.865 us; speedup vs baseline: 2.3758x; 2.2062x over previous
//
#include <hip/hip_runtime.h>
#include <hip/hip_bf16.h>

typedef __attribute__((ext_vector_type(8))) short bf16x8;
typedef __attribute__((ext_vector_type(4))) float f32x4;

#define NB 4096
#define ND 512
#define MARGIN_F 0.2f

// order-preserving float -> uint encoding for atomicMax.
__device__ __forceinline__ unsigned int enc_f32(float f) {
    unsigned int b = __float_as_uint(f);
    return (b & 0x80000000u) ? ~b : (b | 0x80000000u);
}

__device__ __forceinline__ float dec_f32(unsigned int e) {
    unsigned int b = (e & 0x80000000u) ? (e & 0x7fffffffu) : ~e;
    return __uint_as_float(b);
}

__device__ __forceinline__ void gld_lds16(const void* g, void* l) {
    __builtin_amdgcn_global_load_lds((__attribute__((address_space(1))) void*)g,
                                     (__attribute__((address_space(3))) void*)l,
                                     16, 0, 0);
}

// branchless dynamic element select from f32x4 (constant extracts + cndmask)
__device__ __forceinline__ float selv(f32x4 v, int r) {
    float s01 = (r & 1) ? v[1] : v[0];
    float s23 = (r & 1) ? v[3] : v[2];
    return (r & 2) ? s23 : s01;
}

// ---------------------------------------------------------------------------
// Prep: fp32 -> bf16 fragment-swizzled convert (both matrices), grid 2048.
// Blocks [0,16) additionally zero the 4096-entry rowmax array.
// Layout: chunk (rb16 = row/16, cb = col/32) is 1KB at (rb16*16+cb)*1024;
// within chunk lane L = (row%16) | (((col%32)/8)<<4) holds 8 bf16 at L*16.
// ---------------------------------------------------------------------------
__global__ __launch_bounds__(256) void k_prep(const float* __restrict__ zs,
                                              const float* __restrict__ zi,
                                              __hip_bfloat16* __restrict__ outb,
                                              unsigned int* __restrict__ rowmax) {
    const int bid = blockIdx.x;
    if (bid < 16) rowmax[bid * 256 + threadIdx.x] = 0u;

    int gid = bid * 256 + threadIdx.x;   // [0, 2*4096*64)
    int mat = gid >> 18;                 // 0 = zs, 1 = zi
    int t   = gid & 0x3FFFF;
    int si  = t >> 6;
    int L   = t & 63;
    const float* src = mat ? zi : zs;
    int row = ((si >> 4) << 4) | (L & 15);
    int col = ((si & 15) << 5) | (((L >> 4) & 3) << 3);
    const float4* p = (const float4*)(src + (size_t)row * ND + col);
    float4 f0 = p[0];
    float4 f1 = p[1];
    union { __hip_bfloat16 h[8]; bf16x8 v; } u;
    u.h[0] = __float2bfloat16(f0.x);
    u.h[1] = __float2bfloat16(f0.y);
    u.h[2] = __float2bfloat16(f0.z);
    u.h[3] = __float2bfloat16(f0.w);
    u.h[4] = __float2bfloat16(f1.x);
    u.h[5] = __float2bfloat16(f1.y);
    u.h[6] = __float2bfloat16(f1.z);
    u.h[7] = __float2bfloat16(f1.w);
    bf16x8* dst = (bf16x8*)(outb + ((size_t)mat << 21) + ((size_t)si << 9) + (L << 3));
    *dst = u.v;
}

// ---------------------------------------------------------------------------
// 256x256 tile GEMM (S = Zs . Zi^T), BK=64, 8 waves (2M x 4N), wave tile
// 128x64. Quadrant schedule, IDENTICAL structure/ledger to round-2 (which
// was correctness-verified), but with ALL accumulators and fragments as
// individually NAMED variables: rounds 1-2 showed ~1 GB of scratch
// writebacks == exactly one store per MFMA result, i.e. the acc[8][4]
// alloca never got SROA-promoted (rule #20). Named vars make every access
// a compile-time register reference.
//
// Staging ledger (2 global_load_lds per thread per half-tile; h = {0:A-h0,
// 1:A-h1, 2:B-h0, 3:B-h1}):
//   prologue: T0.h0..h3 + T1.h2,h3 ; __syncthreads (full drain, once).
//   iter kt:  P0 stages T(kt+1).h0 | P1 stages T(kt+1).h1 (opposite parity;
//             A halves are read every phase of the CURRENT parity)
//             P3 stages T(kt+2).h2,h3 (same parity; B reads done in P2)
//   boundary (end P3): queue = [T(kt+1).h2h3(4), T(kt+1).h0(2), h1(2),
//   T(kt+2).h2h3(4)] -> s_waitcnt vmcnt(4) retires exactly all of T(kt+1),
//   keeps T(kt+2).h2h3 in flight. vmcnt(0) only at kt==6 (tail).
// ---------------------------------------------------------------------------
__global__ __launch_bounds__(512, 2) void k_gemm_rowmax(const __hip_bfloat16* __restrict__ zsb,
                                                        const __hip_bfloat16* __restrict__ zib,
                                                        const int* __restrict__ labels,
                                                        unsigned int* __restrict__ rowmax,
                                                        float* __restrict__ p_diag) {
    __shared__ __align__(16) unsigned char lds[131072];
    __shared__ int labA[256];
    __shared__ int labB[256];

    const int tid = threadIdx.x;
    // XCD-aware swizzle: each XCD (bid&7) owns a 4(bx) x 8(by) tile region
    // -> working set 4 B-panels + 8 A-panels = 3 MB < 4 MB per-XCD L2.
    const int bid = blockIdx.x;
    const int xcd = bid & 7, lid = bid >> 3;
    const int bx = ((xcd & 3) << 2) | (lid & 3);
    const int by = ((xcd >> 2) << 3) | (lid >> 2);

    if (tid < 256) labA[tid] = labels[by * 256 + tid];
    else           labB[tid & 255] = labels[bx * 256 + (tid & 255)];

    const char* gA = (const char*)zsb;
    const char* gB = (const char*)zib;
    const int inner = (tid & 127) << 4;        // byte offset within 2KB (rb, kt) strip
    const int aB16 = by * 16 + (tid >> 7);     // staging row-block base (A)
    const int bB16 = bx * 16 + (tid >> 7);     // staging row-block base (B)

    // STAGE(kt, h): 2 x 16B per thread into half-tile slot h of buf[kt&1].
#define STAGE(kt, h) do {                                                          \
        const char* _g = ((h) & 2) ? gB : gA;                                      \
        int _rb = (((h) & 2) ? bB16 : aB16) + (((h) & 1) << 3);                    \
        unsigned _ld = (((kt) & 1) << 16) + ((h) << 14) + (tid << 4);              \
        gld_lds16(_g + (((size_t)_rb) << 14) + ((kt) << 11) + inner, lds + _ld);   \
        gld_lds16(_g + (((size_t)(_rb + 4)) << 14) + ((kt) << 11) + inner,         \
                  lds + _ld + 8192);                                               \
    } while (0)

    const int w = tid >> 6, lane = tid & 63;
    const int w_m = w >> 2, w_n = w & 3;
    const unsigned fragOff = (unsigned)(lane << 4);
    const unsigned aBase = (unsigned)(w_m << 14) + fragOff;
    const unsigned bBase = 32768u + (unsigned)((w_n >> 1) << 14)
                         + (unsigned)(((w_n & 1) << 2) << 11) + fragOff;

    const f32x4 Z4 = (f32x4){0.f, 0.f, 0.f, 0.f};
    f32x4 acc00=Z4, acc01=Z4, acc02=Z4, acc03=Z4;
    f32x4 acc10=Z4, acc11=Z4, acc12=Z4, acc13=Z4;
    f32x4 acc20=Z4, acc21=Z4, acc22=Z4, acc23=Z4;
    f32x4 acc30=Z4, acc31=Z4, acc32=Z4, acc33=Z4;
    f32x4 acc40=Z4, acc41=Z4, acc42=Z4, acc43=Z4;
    f32x4 acc50=Z4, acc51=Z4, acc52=Z4, acc53=Z4;
    f32x4 acc60=Z4, acc61=Z4, acc62=Z4, acc63=Z4;
    f32x4 acc70=Z4, acc71=Z4, acc72=Z4, acc73=Z4;
    bf16x8 a_0, a_1, a_2, a_3, b_0, b_1, b_2, b_3;

#define MF(A, B, C) __builtin_amdgcn_mfma_f32_16x16x32_bf16((A), (B), (C), 0, 0, 0)
#define LDB(koff)                                                              \
    b_0 = *(const bf16x8*)(lds + par + bBase + (0 << 11) + (koff));            \
    b_1 = *(const bf16x8*)(lds + par + bBase + (1 << 11) + (koff));            \
    b_2 = *(const bf16x8*)(lds + par + bBase + (2 << 11) + (koff));            \
    b_3 = *(const bf16x8*)(lds + par + bBase + (3 << 11) + (koff));
#define LDA(mh, koff)                                                          \
    a_0 = *(const bf16x8*)(lds + par + aBase + ((((mh) << 2) + 0) << 11) + (koff)); \
    a_1 = *(const bf16x8*)(lds + par + aBase + ((((mh) << 2) + 1) << 11) + (koff)); \
    a_2 = *(const bf16x8*)(lds + par + aBase + ((((mh) << 2) + 2) << 11) + (koff)); \
    a_3 = *(const bf16x8*)(lds + par + aBase + ((((mh) << 2) + 3) << 11) + (koff));
#define ROW4(A, R)                                                             \
    acc##R##0 = MF((A), b_0, acc##R##0);                                       \
    acc##R##1 = MF((A), b_1, acc##R##1);                                       \
    acc##R##2 = MF((A), b_2, acc##R##2);                                       \
    acc##R##3 = MF((A), b_3, acc##R##3);

    // prologue: T0 fully + T1's B halves, then one full drain
    STAGE(0, 0); STAGE(0, 1); STAGE(0, 2); STAGE(0, 3);
    STAGE(1, 2); STAGE(1, 3);
    __syncthreads();

#pragma unroll
    for (int kt = 0; kt < 8; ++kt) {
        const unsigned par = (unsigned)((kt & 1) << 16);

        // ---- P0: b0(k0) + a(mh0,k0); stage T(kt+1).h0; MFMA rows 0..3 ----
        LDB(0)
        LDA(0, 0)
        if (kt < 7) STAGE(kt + 1, 0);
        __builtin_amdgcn_s_setprio(1);
        ROW4(a_0, 0) ROW4(a_1, 1) ROW4(a_2, 2) ROW4(a_3, 3)
        __builtin_amdgcn_s_setprio(0);
        __builtin_amdgcn_s_barrier();

        // ---- P1: a(mh1,k0); stage T(kt+1).h1; MFMA rows 4..7 ----
        LDA(1, 0)
        if (kt < 7) STAGE(kt + 1, 1);
        __builtin_amdgcn_s_setprio(1);
        ROW4(a_0, 4) ROW4(a_1, 5) ROW4(a_2, 6) ROW4(a_3, 7)
        __builtin_amdgcn_s_setprio(0);
        __builtin_amdgcn_s_barrier();

        // ---- P2: b1(k1) + a(mh0,k1); MFMA rows 0..3 ----
        LDB(1024)
        LDA(0, 1024)
        __builtin_amdgcn_s_setprio(1);
        ROW4(a_0, 0) ROW4(a_1, 1) ROW4(a_2, 2) ROW4(a_3, 3)
        __builtin_amdgcn_s_setprio(0);
        __builtin_amdgcn_s_barrier();

        // ---- P3: a(mh1,k1); stage T(kt+2).h2,h3; MFMA rows 4..7; boundary ----
        LDA(1, 1024)
        if (kt < 6) { STAGE(kt + 2, 2); STAGE(kt + 2, 3); }
        __builtin_amdgcn_s_setprio(1);
        ROW4(a_0, 4) ROW4(a_1, 5) ROW4(a_2, 6) ROW4(a_3, 7)
        __builtin_amdgcn_s_setprio(0);
        if (kt < 6) {
            asm volatile("s_waitcnt vmcnt(4)" ::: "memory");   // all of T(kt+1) landed
            __builtin_amdgcn_s_barrier();
        } else if (kt == 6) {
            asm volatile("s_waitcnt vmcnt(0)" ::: "memory");   // tail: T7 fully landed
            __builtin_amdgcn_s_barrier();
        }
    }
#undef STAGE
#undef LDA
#undef LDB
#undef ROW4

    // epilogue: C/D layout col = lane&15, row = (lane>>4)*4 + reg
    const int quad = lane >> 4;
    const int lcol = lane & 15;
    const int epiBase = by * 256 + w_m * 128 + quad * 4;

    const int lb_0 = labB[w_n * 64 + 0 * 16 + lcol];
    const int lb_1 = labB[w_n * 64 + 1 * 16 + lcol];
    const int lb_2 = labB[w_n * 64 + 2 * 16 + lcol];
    const int lb_3 = labB[w_n * 64 + 3 * 16 + lcol];

#define EPIV(m, n, LB) {                                                       \
        float v0 = acc##m##n[0], v1 = acc##m##n[1];                            \
        float v2 = acc##m##n[2], v3 = acc##m##n[3];                            \
        if (la0 != (LB) && v0 > mx0) mx0 = v0;                                 \
        if (la1 != (LB) && v1 > mx1) mx1 = v1;                                 \
        if (la2 != (LB) && v2 > mx2) mx2 = v2;                                 \
        if (la3 != (LB) && v3 > mx3) mx3 = v3; }
#define EPIRED(m, r, MX) {                                                     \
        float mm = (MX);                                                       \
        mm = fmaxf(mm, __shfl_xor(mm, 1));                                     \
        mm = fmaxf(mm, __shfl_xor(mm, 2));                                     \
        mm = fmaxf(mm, __shfl_xor(mm, 4));                                     \
        mm = fmaxf(mm, __shfl_xor(mm, 8));                                     \
        if (lcol == 0 && mm > -2.9e38f)                                        \
            atomicMax(&rowmax[epiBase + (m) * 16 + (r)], enc_f32(mm)); }
#define EPIMS(m) {                                                             \
        int la0 = labA[w_m * 128 + (m) * 16 + quad * 4 + 0];                   \
        int la1 = labA[w_m * 128 + (m) * 16 + quad * 4 + 1];                   \
        int la2 = labA[w_m * 128 + (m) * 16 + quad * 4 + 2];                   \
        int la3 = labA[w_m * 128 + (m) * 16 + quad * 4 + 3];                   \
        float mx0 = -3.0e38f, mx1 = -3.0e38f, mx2 = -3.0e38f, mx3 = -3.0e38f;  \
        EPIV(m, 0, lb_0) EPIV(m, 1, lb_1) EPIV(m, 2, lb_2) EPIV(m, 3, lb_3)    \
        EPIRED(m, 0, mx0) EPIRED(m, 1, mx1) EPIRED(m, 2, mx2) EPIRED(m, 3, mx3) }

    EPIMS(0) EPIMS(1) EPIMS(2) EPIMS(3)
    EPIMS(4) EPIMS(5) EPIMS(6) EPIMS(7)
#undef EPIMS
#undef EPIRED
#undef EPIV

    // diagonal blocks: p[a] = 1 - S[a][a]. Wave covers the diagonal iff its
    // 64-col window lies in its 128-row window: (w_n>>1)==w_m. Diag frag
    // pairs are ms = (w_n&1)*4 + ns with frag-row lcol, element r = lcol&3
    // (valid iff quad == lcol>>2). Runtime-ms handled by uniform ternary;
    // runtime-r by branchless constant-extract select (no dynamic indexing).
    if (bx == by && (w_n >> 1) == w_m && (lcol >> 2) == quad) {
        int r = lcol & 3;
        f32x4 d0 = (w_n & 1) ? acc40 : acc00;
        f32x4 d1 = (w_n & 1) ? acc51 : acc11;
        f32x4 d2 = (w_n & 1) ? acc62 : acc22;
        f32x4 d3 = (w_n & 1) ? acc73 : acc33;
        int base = by * 256 + w_m * 128 + ((w_n & 1) << 6) + lcol;
        p_diag[base +  0] = 1.0f - selv(d0, r);
        p_diag[base + 16] = 1.0f - selv(d1, r);
        p_diag[base + 32] = 1.0f - selv(d2, r);
        p_diag[base + 48] = 1.0f - selv(d3, r);
    }
}

// ---------------------------------------------------------------------------
// Finalize: has_neg = (rowmax != 0); n = 1 - dec(rowmax);
// per = relu(p - n + margin); masked mean -> out[0]
// ---------------------------------------------------------------------------
__global__ __launch_bounds__(1024) void k_finalize(const unsigned int* __restrict__ rowmax,
                                                   const float* __restrict__ p_diag,
                                                   float* __restrict__ out) {
    int tid = threadIdx.x;
    float sum = 0.0f;
    int cnt = 0;
#pragma unroll
    for (int it = 0; it < 4; ++it) {
        int a = tid + it * 1024;
        unsigned int e = rowmax[a];
        if (e != 0u) {
            float n = 1.0f - dec_f32(e);
            float per = p_diag[a] - n + MARGIN_F;
            if (per > 0.0f) sum += per;
            cnt++;
        }
    }
#pragma unroll
    for (int off = 32; off > 0; off >>= 1) {
        sum += __shfl_xor(sum, off);
        cnt += __shfl_xor(cnt, off);
    }
    __shared__ float sSum[16];
    __shared__ int sCnt[16];
    int w = tid >> 6, lane = tid & 63;
    if (lane == 0) { sSum[w] = sum; sCnt[w] = cnt; }
    __syncthreads();
    if (tid == 0) {
        float ts = 0.0f;
        int tc = 0;
#pragma unroll
        for (int i = 0; i < 16; ++i) { ts += sSum[i]; tc += sCnt[i]; }
        out[0] = (tc > 0) ? ts / (float)tc : 0.0f;
    }
}

extern "C" void kernel_launch(void* const* d_in, const int* in_sizes, int n_in,
                              void* d_out, int out_size, void* d_ws, size_t ws_size,
                              hipStream_t stream) {
    (void)in_sizes; (void)n_in; (void)out_size; (void)ws_size;
    const float* zs = (const float*)d_in[0];
    const float* zi = (const float*)d_in[1];
    const int* labels = (const int*)d_in[2];
    float* out = (float*)d_out;

    char* ws = (char*)d_ws;
    __hip_bfloat16* zb = (__hip_bfloat16*)ws;                       // 8 MB (zs then zi, swizzled)
    unsigned int* rowmax = (unsigned int*)(ws + (8u << 20));        // 16 KB
    float* p_diag = (float*)(ws + (8u << 20) + 16384);              // 16 KB

    k_prep<<<2048, 256, 0, stream>>>(zs, zi, zb, rowmax);
    k_gemm_rowmax<<<256, 512, 0, stream>>>(zb, zb + (size_t)NB * ND, labels, rowmax, p_diag);
    k_finalize<<<1, 1024, 0, stream>>>(rowmax, p_diag, out);
}

// Round 4
// 97.797 us; speedup vs baseline: 2.4261x; 1.0211x over previous
//
#include <hip/hip_runtime.h>
#include <hip/hip_bf16.h>

typedef __attribute__((ext_vector_type(8))) short bf16x8;
typedef __attribute__((ext_vector_type(4))) float f32x4;

#define NB 4096
#define ND 512
#define MARGIN_F 0.2f

// order-preserving float -> uint encoding for atomicMax.
__device__ __forceinline__ unsigned int enc_f32(float f) {
    unsigned int b = __float_as_uint(f);
    return (b & 0x80000000u) ? ~b : (b | 0x80000000u);
}

__device__ __forceinline__ float dec_f32(unsigned int e) {
    unsigned int b = (e & 0x80000000u) ? (e & 0x7fffffffu) : ~e;
    return __uint_as_float(b);
}

__device__ __forceinline__ void gld_lds16(const void* g, void* l) {
    __builtin_amdgcn_global_load_lds((__attribute__((address_space(1))) void*)g,
                                     (__attribute__((address_space(3))) void*)l,
                                     16, 0, 0);
}

// branchless dynamic element select from f32x4 (constant extracts + cndmask)
__device__ __forceinline__ float selv(f32x4 v, int r) {
    float s01 = (r & 1) ? v[1] : v[0];
    float s23 = (r & 1) ? v[3] : v[2];
    return (r & 2) ? s23 : s01;
}

// ---------------------------------------------------------------------------
// Prep: fp32 -> bf16 fragment-swizzled convert (both matrices), grid 2048.
// Blocks [0,16) additionally zero the 4096-entry rowmax array.
// Layout: chunk (rb16 = row/16, cb = col/32) is 1KB at (rb16*16+cb)*1024;
// within chunk lane L = (row%16) | (((col%32)/8)<<4) holds 8 bf16 at L*16.
// ---------------------------------------------------------------------------
__global__ __launch_bounds__(256) void k_prep(const float* __restrict__ zs,
                                              const float* __restrict__ zi,
                                              __hip_bfloat16* __restrict__ outb,
                                              unsigned int* __restrict__ rowmax) {
    const int bid = blockIdx.x;
    if (bid < 16) rowmax[bid * 256 + threadIdx.x] = 0u;

    int gid = bid * 256 + threadIdx.x;   // [0, 2*4096*64)
    int mat = gid >> 18;                 // 0 = zs, 1 = zi
    int t   = gid & 0x3FFFF;
    int si  = t >> 6;
    int L   = t & 63;
    const float* src = mat ? zi : zs;
    int row = ((si >> 4) << 4) | (L & 15);
    int col = ((si & 15) << 5) | (((L >> 4) & 3) << 3);
    const float4* p = (const float4*)(src + (size_t)row * ND + col);
    float4 f0 = p[0];
    float4 f1 = p[1];
    union { __hip_bfloat16 h[8]; bf16x8 v; } u;
    u.h[0] = __float2bfloat16(f0.x);
    u.h[1] = __float2bfloat16(f0.y);
    u.h[2] = __float2bfloat16(f0.z);
    u.h[3] = __float2bfloat16(f0.w);
    u.h[4] = __float2bfloat16(f1.x);
    u.h[5] = __float2bfloat16(f1.y);
    u.h[6] = __float2bfloat16(f1.z);
    u.h[7] = __float2bfloat16(f1.w);
    bf16x8* dst = (bf16x8*)(outb + ((size_t)mat << 21) + ((size_t)si << 9) + (L << 3));
    *dst = u.v;
}

// ---------------------------------------------------------------------------
// 256x256 tile GEMM (S = Zs . Zi^T), BK=64, 8 waves (2M x 4N), wave tile
// 128x64. Named accumulators (rule #20: rounds 1-2 lost ~1 GB to an
// unpromoted acc alloca). Staging/vmcnt ledger identical to the verified
// round-3 version. NEW this round: m201's exact two-barrier phase skeleton
//   [ds_reads ; STAGE ; s_barrier ; lgkmcnt(0) ; sched_barrier(0) ;
//    setprio(1) ; 16 MFMA ; setprio(0) ; s_barrier]
// -- all 8 waves' LDS reads are issued before any wave's MFMA cluster
// (reads serviced while waiting AT the barrier), and the setprio-wrapped
// MFMA cluster gets the T5 role-split (m218b: +21-39% only with this
// structure). Round-3's single-barrier phases left ~7x stall per K-tile.
//
// Staging ledger (2 global_load_lds per thread per half-tile; h = {0:A-h0,
// 1:A-h1, 2:B-h0, 3:B-h1}):
//   prologue: T0.h0..h3 + T1.h2,h3 ; __syncthreads (full drain, once).
//   iter kt:  P0 stages T(kt+1).h0 | P1 stages T(kt+1).h1 (opposite parity)
//             P3 stages T(kt+2).h2,h3 (same parity; B reads of this buffer
//             retired by P2's lgkmcnt(0) + barrier)
//   boundary (end P3): queue = [T(kt+1).h2h3(4), T(kt+1).h0(2), h1(2),
//   T(kt+2).h2h3(4)] -> s_waitcnt vmcnt(4) retires exactly all of T(kt+1),
//   keeps T(kt+2).h2h3 in flight. vmcnt(0) only at kt==6 (tail).
// ---------------------------------------------------------------------------
__global__ __launch_bounds__(512, 2) void k_gemm_rowmax(const __hip_bfloat16* __restrict__ zsb,
                                                        const __hip_bfloat16* __restrict__ zib,
                                                        const int* __restrict__ labels,
                                                        unsigned int* __restrict__ rowmax,
                                                        float* __restrict__ p_diag) {
    __shared__ __align__(16) unsigned char lds[131072];
    __shared__ int labA[256];
    __shared__ int labB[256];

    const int tid = threadIdx.x;
    // XCD-aware swizzle: each XCD (bid&7) owns a 4(bx) x 8(by) tile region
    // -> working set 4 B-panels + 8 A-panels = 3 MB < 4 MB per-XCD L2.
    const int bid = blockIdx.x;
    const int xcd = bid & 7, lid = bid >> 3;
    const int bx = ((xcd & 3) << 2) | (lid & 3);
    const int by = ((xcd >> 2) << 3) | (lid >> 2);

    if (tid < 256) labA[tid] = labels[by * 256 + tid];
    else           labB[tid & 255] = labels[bx * 256 + (tid & 255)];

    const char* gA = (const char*)zsb;
    const char* gB = (const char*)zib;
    const int inner = (tid & 127) << 4;        // byte offset within 2KB (rb, kt) strip
    const int aB16 = by * 16 + (tid >> 7);     // staging row-block base (A)
    const int bB16 = bx * 16 + (tid >> 7);     // staging row-block base (B)

    // STAGE(kt, h): 2 x 16B per thread into half-tile slot h of buf[kt&1].
#define STAGE(kt, h) do {                                                          \
        const char* _g = ((h) & 2) ? gB : gA;                                      \
        int _rb = (((h) & 2) ? bB16 : aB16) + (((h) & 1) << 3);                    \
        unsigned _ld = (((kt) & 1) << 16) + ((h) << 14) + (tid << 4);              \
        gld_lds16(_g + (((size_t)_rb) << 14) + ((kt) << 11) + inner, lds + _ld);   \
        gld_lds16(_g + (((size_t)(_rb + 4)) << 14) + ((kt) << 11) + inner,         \
                  lds + _ld + 8192);                                               \
    } while (0)

    const int w = tid >> 6, lane = tid & 63;
    const int w_m = w >> 2, w_n = w & 3;
    const unsigned fragOff = (unsigned)(lane << 4);
    const unsigned aBase = (unsigned)(w_m << 14) + fragOff;
    const unsigned bBase = 32768u + (unsigned)((w_n >> 1) << 14)
                         + (unsigned)(((w_n & 1) << 2) << 11) + fragOff;

    const f32x4 Z4 = (f32x4){0.f, 0.f, 0.f, 0.f};
    f32x4 acc00=Z4, acc01=Z4, acc02=Z4, acc03=Z4;
    f32x4 acc10=Z4, acc11=Z4, acc12=Z4, acc13=Z4;
    f32x4 acc20=Z4, acc21=Z4, acc22=Z4, acc23=Z4;
    f32x4 acc30=Z4, acc31=Z4, acc32=Z4, acc33=Z4;
    f32x4 acc40=Z4, acc41=Z4, acc42=Z4, acc43=Z4;
    f32x4 acc50=Z4, acc51=Z4, acc52=Z4, acc53=Z4;
    f32x4 acc60=Z4, acc61=Z4, acc62=Z4, acc63=Z4;
    f32x4 acc70=Z4, acc71=Z4, acc72=Z4, acc73=Z4;
    bf16x8 a_0, a_1, a_2, a_3, b_0, b_1, b_2, b_3;

#define MF(A, B, C) __builtin_amdgcn_mfma_f32_16x16x32_bf16((A), (B), (C), 0, 0, 0)
#define LDB(koff)                                                              \
    b_0 = *(const bf16x8*)(lds + par + bBase + (0 << 11) + (koff));            \
    b_1 = *(const bf16x8*)(lds + par + bBase + (1 << 11) + (koff));            \
    b_2 = *(const bf16x8*)(lds + par + bBase + (2 << 11) + (koff));            \
    b_3 = *(const bf16x8*)(lds + par + bBase + (3 << 11) + (koff));
#define LDA(mh, koff)                                                          \
    a_0 = *(const bf16x8*)(lds + par + aBase + ((((mh) << 2) + 0) << 11) + (koff)); \
    a_1 = *(const bf16x8*)(lds + par + aBase + ((((mh) << 2) + 1) << 11) + (koff)); \
    a_2 = *(const bf16x8*)(lds + par + aBase + ((((mh) << 2) + 2) << 11) + (koff)); \
    a_3 = *(const bf16x8*)(lds + par + aBase + ((((mh) << 2) + 3) << 11) + (koff));
#define ROW4(A, R)                                                             \
    acc##R##0 = MF((A), b_0, acc##R##0);                                       \
    acc##R##1 = MF((A), b_1, acc##R##1);                                       \
    acc##R##2 = MF((A), b_2, acc##R##2);                                       \
    acc##R##3 = MF((A), b_3, acc##R##3);
    // m201 phase discipline: barrier -> drain lgkm -> pin order -> prio MFMA
#define PHASE_SYNC()                                                           \
    __builtin_amdgcn_s_barrier();                                              \
    asm volatile("s_waitcnt lgkmcnt(0)" ::: "memory");                         \
    __builtin_amdgcn_sched_barrier(0);

    // prologue: T0 fully + T1's B halves, then one full drain
    STAGE(0, 0); STAGE(0, 1); STAGE(0, 2); STAGE(0, 3);
    STAGE(1, 2); STAGE(1, 3);
    __syncthreads();

#pragma unroll
    for (int kt = 0; kt < 8; ++kt) {
        const unsigned par = (unsigned)((kt & 1) << 16);

        // ---- P0: b0(k0) + a(mh0,k0); stage T(kt+1).h0; MFMA rows 0..3 ----
        LDB(0)
        LDA(0, 0)
        if (kt < 7) STAGE(kt + 1, 0);
        PHASE_SYNC()
        __builtin_amdgcn_s_setprio(1);
        ROW4(a_0, 0) ROW4(a_1, 1) ROW4(a_2, 2) ROW4(a_3, 3)
        __builtin_amdgcn_s_setprio(0);
        __builtin_amdgcn_s_barrier();

        // ---- P1: a(mh1,k0); stage T(kt+1).h1; MFMA rows 4..7 ----
        LDA(1, 0)
        if (kt < 7) STAGE(kt + 1, 1);
        PHASE_SYNC()
        __builtin_amdgcn_s_setprio(1);
        ROW4(a_0, 4) ROW4(a_1, 5) ROW4(a_2, 6) ROW4(a_3, 7)
        __builtin_amdgcn_s_setprio(0);
        __builtin_amdgcn_s_barrier();

        // ---- P2: b1(k1) + a(mh0,k1); MFMA rows 0..3 ----
        LDB(1024)
        LDA(0, 1024)
        PHASE_SYNC()
        __builtin_amdgcn_s_setprio(1);
        ROW4(a_0, 0) ROW4(a_1, 1) ROW4(a_2, 2) ROW4(a_3, 3)
        __builtin_amdgcn_s_setprio(0);
        __builtin_amdgcn_s_barrier();

        // ---- P3: a(mh1,k1); stage T(kt+2).h2,h3; MFMA rows 4..7; boundary ----
        LDA(1, 1024)
        if (kt < 6) { STAGE(kt + 2, 2); STAGE(kt + 2, 3); }
        PHASE_SYNC()
        __builtin_amdgcn_s_setprio(1);
        ROW4(a_0, 4) ROW4(a_1, 5) ROW4(a_2, 6) ROW4(a_3, 7)
        __builtin_amdgcn_s_setprio(0);
        if (kt < 6) {
            asm volatile("s_waitcnt vmcnt(4)" ::: "memory");   // all of T(kt+1) landed
            __builtin_amdgcn_s_barrier();
        } else if (kt == 6) {
            asm volatile("s_waitcnt vmcnt(0)" ::: "memory");   // tail: T7 fully landed
            __builtin_amdgcn_s_barrier();
        }
    }
#undef STAGE
#undef LDA
#undef LDB
#undef ROW4
#undef PHASE_SYNC

    // epilogue: C/D layout col = lane&15, row = (lane>>4)*4 + reg
    const int quad = lane >> 4;
    const int lcol = lane & 15;
    const int epiBase = by * 256 + w_m * 128 + quad * 4;

    const int lb_0 = labB[w_n * 64 + 0 * 16 + lcol];
    const int lb_1 = labB[w_n * 64 + 1 * 16 + lcol];
    const int lb_2 = labB[w_n * 64 + 2 * 16 + lcol];
    const int lb_3 = labB[w_n * 64 + 3 * 16 + lcol];

#define EPIV(m, n, LB) {                                                       \
        float v0 = acc##m##n[0], v1 = acc##m##n[1];                            \
        float v2 = acc##m##n[2], v3 = acc##m##n[3];                            \
        if (la0 != (LB) && v0 > mx0) mx0 = v0;                                 \
        if (la1 != (LB) && v1 > mx1) mx1 = v1;                                 \
        if (la2 != (LB) && v2 > mx2) mx2 = v2;                                 \
        if (la3 != (LB) && v3 > mx3) mx3 = v3; }
#define EPIRED(m, r, MX) {                                                     \
        float mm = (MX);                                                       \
        mm = fmaxf(mm, __shfl_xor(mm, 1));                                     \
        mm = fmaxf(mm, __shfl_xor(mm, 2));                                     \
        mm = fmaxf(mm, __shfl_xor(mm, 4));                                     \
        mm = fmaxf(mm, __shfl_xor(mm, 8));                                     \
        if (lcol == 0 && mm > -2.9e38f)                                        \
            atomicMax(&rowmax[epiBase + (m) * 16 + (r)], enc_f32(mm)); }
#define EPIMS(m) {                                                             \
        int la0 = labA[w_m * 128 + (m) * 16 + quad * 4 + 0];                   \
        int la1 = labA[w_m * 128 + (m) * 16 + quad * 4 + 1];                   \
        int la2 = labA[w_m * 128 + (m) * 16 + quad * 4 + 2];                   \
        int la3 = labA[w_m * 128 + (m) * 16 + quad * 4 + 3];                   \
        float mx0 = -3.0e38f, mx1 = -3.0e38f, mx2 = -3.0e38f, mx3 = -3.0e38f;  \
        EPIV(m, 0, lb_0) EPIV(m, 1, lb_1) EPIV(m, 2, lb_2) EPIV(m, 3, lb_3)    \
        EPIRED(m, 0, mx0) EPIRED(m, 1, mx1) EPIRED(m, 2, mx2) EPIRED(m, 3, mx3) }

    EPIMS(0) EPIMS(1) EPIMS(2) EPIMS(3)
    EPIMS(4) EPIMS(5) EPIMS(6) EPIMS(7)
#undef EPIMS
#undef EPIRED
#undef EPIV

    // diagonal blocks: p[a] = 1 - S[a][a]. Wave covers the diagonal iff its
    // 64-col window lies in its 128-row window: (w_n>>1)==w_m. Diag frag
    // pairs are ms = (w_n&1)*4 + ns with frag-row lcol, element r = lcol&3
    // (valid iff quad == lcol>>2). Runtime-ms handled by uniform ternary;
    // runtime-r by branchless constant-extract select (no dynamic indexing).
    if (bx == by && (w_n >> 1) == w_m && (lcol >> 2) == quad) {
        int r = lcol & 3;
        f32x4 d0 = (w_n & 1) ? acc40 : acc00;
        f32x4 d1 = (w_n & 1) ? acc51 : acc11;
        f32x4 d2 = (w_n & 1) ? acc62 : acc22;
        f32x4 d3 = (w_n & 1) ? acc73 : acc33;
        int base = by * 256 + w_m * 128 + ((w_n & 1) << 6) + lcol;
        p_diag[base +  0] = 1.0f - selv(d0, r);
        p_diag[base + 16] = 1.0f - selv(d1, r);
        p_diag[base + 32] = 1.0f - selv(d2, r);
        p_diag[base + 48] = 1.0f - selv(d3, r);
    }
}

// ---------------------------------------------------------------------------
// Finalize: has_neg = (rowmax != 0); n = 1 - dec(rowmax);
// per = relu(p - n + margin); masked mean -> out[0]
// ---------------------------------------------------------------------------
__global__ __launch_bounds__(1024) void k_finalize(const unsigned int* __restrict__ rowmax,
                                                   const float* __restrict__ p_diag,
                                                   float* __restrict__ out) {
    int tid = threadIdx.x;
    float sum = 0.0f;
    int cnt = 0;
#pragma unroll
    for (int it = 0; it < 4; ++it) {
        int a = tid + it * 1024;
        unsigned int e = rowmax[a];
        if (e != 0u) {
            float n = 1.0f - dec_f32(e);
            float per = p_diag[a] - n + MARGIN_F;
            if (per > 0.0f) sum += per;
            cnt++;
        }
    }
#pragma unroll
    for (int off = 32; off > 0; off >>= 1) {
        sum += __shfl_xor(sum, off);
        cnt += __shfl_xor(cnt, off);
    }
    __shared__ float sSum[16];
    __shared__ int sCnt[16];
    int w = tid >> 6, lane = tid & 63;
    if (lane == 0) { sSum[w] = sum; sCnt[w] = cnt; }
    __syncthreads();
    if (tid == 0) {
        float ts = 0.0f;
        int tc = 0;
#pragma unroll
        for (int i = 0; i < 16; ++i) { ts += sSum[i]; tc += sCnt[i]; }
        out[0] = (tc > 0) ? ts / (float)tc : 0.0f;
    }
}

extern "C" void kernel_launch(void* const* d_in, const int* in_sizes, int n_in,
                              void* d_out, int out_size, void* d_ws, size_t ws_size,
                              hipStream_t stream) {
    (void)in_sizes; (void)n_in; (void)out_size; (void)ws_size;
    const float* zs = (const float*)d_in[0];
    const float* zi = (const float*)d_in[1];
    const int* labels = (const int*)d_in[2];
    float* out = (float*)d_out;

    char* ws = (char*)d_ws;
    __hip_bfloat16* zb = (__hip_bfloat16*)ws;                       // 8 MB (zs then zi, swizzled)
    unsigned int* rowmax = (unsigned int*)(ws + (8u << 20));        // 16 KB
    float* p_diag = (float*)(ws + (8u << 20) + 16384);              // 16 KB

    k_prep<<<2048, 256, 0, stream>>>(zs, zi, zb, rowmax);
    k_gemm_rowmax<<<256, 512, 0, stream>>>(zb, zb + (size_t)NB * ND, labels, rowmax, p_diag);
    k_finalize<<<1, 1024, 0, stream>>>(rowmax, p_diag, out);
}